// Round 1
// baseline (367.065 us; speedup 1.0000x reference)
//
#include <hip/hip_runtime.h>
#include <math.h>

#define B_   256
#define QL_  16
#define DL_  512
#define ED_  300
#define NW1  50001
#define K2_  240
#define K4_  192

__device__ __forceinline__ float sigf(float x){ return 1.0f/(1.0f+__expf(-x)); }

__device__ __forceinline__ float dot16(const float (&a)[16], const float* w){
  float s = 0.f;
  #pragma unroll
  for (int i=0;i<4;i++){
    float4 ww = *(const float4*)(w + 4*i);
    s = fmaf(a[4*i+0], ww.x, s);
    s = fmaf(a[4*i+1], ww.y, s);
    s = fmaf(a[4*i+2], ww.z, s);
    s = fmaf(a[4*i+3], ww.w, s);
  }
  return s;
}

// descending by value, ties -> lower index first (JAX top_k semantics)
template<int N>
__device__ void bitonic_desc(float* v, int* id){
  const int tid = threadIdx.x;
  for (int k = 2; k <= N; k <<= 1){
    for (int j = k >> 1; j > 0; j >>= 1){
      __syncthreads();
      for (int i = tid; i < N; i += 256){
        const int l = i ^ j;
        if (l > i){
          const float vi = v[i], vl = v[l];
          const int ii = id[i], il = id[l];
          const bool before_l = (vl > vi) || (vl == vi && il < ii);
          const bool up = ((i & k) == 0);
          if (up == before_l){ v[i]=vl; v[l]=vi; id[i]=il; id[l]=ii; }
        }
      }
    }
  }
  __syncthreads();
}

// ---------------- K0a: normalized query embeddings ----------------
__global__ __launch_bounds__(256) void k_qnorm(
    const float* __restrict__ emb, const int* __restrict__ qtok,
    float* __restrict__ qen)
{
  const int tid = threadIdx.x, b = blockIdx.x;
  const int q = tid >> 4, s = tid & 15;
  const int tok = qtok[(size_t)b*QL_ + q];
  const float* er = emb + (size_t)tok*ED_;
  float ss = 0.f;
  for (int e = s; e < ED_; e += 16){ const float x = er[e]; ss = fmaf(x,x,ss); }
  ss += __shfl_xor(ss,1); ss += __shfl_xor(ss,2);
  ss += __shfl_xor(ss,4); ss += __shfl_xor(ss,8);
  const float inv = 1.f/(sqrtf(ss)+1e-9f);
  float* orow = qen + ((size_t)b*QL_+q)*ED_;
  for (int e = s; e < ED_; e += 16) orow[e] = er[e]*inv;
}

// ---------------- K0b: 1/(norm+eps) for every emb row ----------------
__global__ __launch_bounds__(256) void k_enorm(
    const float* __restrict__ emb, float* __restrict__ embinv)
{
  const int tid = threadIdx.x;
  const int g = tid>>2, sub = tid&3;
  const int row = blockIdx.x*64 + g;
  if (row >= NW1) return;
  const float* er = emb + (size_t)row*ED_;
  float ss = 0.f;
  for (int j = sub; j < 75; j += 4){
    float4 x4v = *(const float4*)(er + 4*j);
    ss = fmaf(x4v.x,x4v.x,ss); ss = fmaf(x4v.y,x4v.y,ss);
    ss = fmaf(x4v.z,x4v.z,ss); ss = fmaf(x4v.w,x4v.w,ss);
  }
  ss += __shfl_xor(ss,1); ss += __shfl_xor(ss,2);
  if (sub == 0) embinv[row] = 1.f/(sqrtf(ss)+1e-9f);
}

// ---------------- K1: cosine sim feat[b,d,q] (both layouts) ----------------
__global__ __launch_bounds__(256) void k_feat(
    const float* __restrict__ emb, const float* __restrict__ embinv,
    const int* __restrict__ dtok, const float* __restrict__ qen,
    float* __restrict__ featdq, float* __restrict__ featqd)
{
  alignas(16) __shared__ float ql[16*304];
  __shared__ int toks[256];
  __shared__ float invl[256];
  const int tid = threadIdx.x;
  const int b = blockIdx.x >> 1, d0 = (blockIdx.x & 1) * 256;
  for (int q=0;q<16;q++)
    for (int e=tid; e<ED_; e+=256)
      ql[q*304+e] = qen[((size_t)b*QL_+q)*ED_ + e];
  {
    const int tok = dtok[(size_t)b*DL_ + d0 + tid];
    toks[tid] = tok;
    invl[tid] = embinv[tok];
  }
  __syncthreads();
  const int g = tid>>2, sub = tid&3;
  const float* e0p = emb + (size_t)toks[4*g+0]*ED_;
  const float* e1p = emb + (size_t)toks[4*g+1]*ED_;
  const float* e2p = emb + (size_t)toks[4*g+2]*ED_;
  const float* e3p = emb + (size_t)toks[4*g+3]*ED_;
  float acc[4][16];
  #pragma unroll
  for (int r=0;r<4;r++)
    #pragma unroll
    for (int q=0;q<16;q++) acc[r][q] = 0.f;
  for (int i=0;i<19;i++){
    const int j = sub + 4*i;
    if (j < 75){
      const int e0 = 4*j;
      float4 d0v = *(const float4*)(e0p + e0);
      float4 d1v = *(const float4*)(e1p + e0);
      float4 d2v = *(const float4*)(e2p + e0);
      float4 d3v = *(const float4*)(e3p + e0);
      #pragma unroll
      for (int q=0;q<16;q++){
        float4 qv = *(const float4*)(&ql[q*304 + e0]);
        acc[0][q] = fmaf(d0v.x,qv.x, fmaf(d0v.y,qv.y, fmaf(d0v.z,qv.z, fmaf(d0v.w,qv.w, acc[0][q]))));
        acc[1][q] = fmaf(d1v.x,qv.x, fmaf(d1v.y,qv.y, fmaf(d1v.z,qv.z, fmaf(d1v.w,qv.w, acc[1][q]))));
        acc[2][q] = fmaf(d2v.x,qv.x, fmaf(d2v.y,qv.y, fmaf(d2v.z,qv.z, fmaf(d2v.w,qv.w, acc[2][q]))));
        acc[3][q] = fmaf(d3v.x,qv.x, fmaf(d3v.y,qv.y, fmaf(d3v.z,qv.z, fmaf(d3v.w,qv.w, acc[3][q]))));
      }
    }
  }
  #pragma unroll
  for (int r=0;r<4;r++)
    #pragma unroll
    for (int q=0;q<16;q++){
      float v = acc[r][q];
      v += __shfl_xor(v, 1);
      v += __shfl_xor(v, 2);
      acc[r][q] = v;
    }
  const int d = d0 + 4*g + sub;
  const float invn = invl[4*g + sub];
  float vs[16];
  #pragma unroll
  for (int q=0;q<16;q++){
    const float v = (sub==0)?acc[0][q]:(sub==1)?acc[1][q]:(sub==2)?acc[2][q]:acc[3][q];
    vs[q] = v * invn;
  }
  float* fo = &featdq[((size_t)b*DL_ + d)*16];
  *(float4*)(fo+0)  = make_float4(vs[0],vs[1],vs[2],vs[3]);
  *(float4*)(fo+4)  = make_float4(vs[4],vs[5],vs[6],vs[7]);
  *(float4*)(fo+8)  = make_float4(vs[8],vs[9],vs[10],vs[11]);
  *(float4*)(fo+12) = make_float4(vs[12],vs[13],vs[14],vs[15]);
  #pragma unroll
  for (int q=0;q<16;q++)
    featqd[((size_t)b*QL_+q)*DL_ + d] = vs[q];
}

// ---------------- K2/K5: (adj @ B) -> GGNN matrix gate -> rep, xproj ----------------
__global__ __launch_bounds__(256) void k_gemm_gate(
    const float* __restrict__ Abase, int amode, const int* __restrict__ doc_ids,
    const float* __restrict__ Bmat, const float* __restrict__ Wg,
    const float* __restrict__ bg, const float* __restrict__ pw,
    const float* __restrict__ pb, float* __restrict__ rep,
    float* __restrict__ xproj, int K, int M, int parts)
{
  extern __shared__ float sm[];
  float* fx  = sm;                    // [K][20] padded
  float* wl  = sm + (size_t)K*20;     // 6*16*16
  float* bl  = wl + 1536;             // 6*16
  float* pwl = bl + 96;               // 16
  const int tid = threadIdx.x;
  const int b = blockIdx.x / parts;
  const int part = blockIdx.x % parts;
  const int m0 = part * 256;

  for (int idx = tid; idx < K*16; idx += 256){
    const int k = idx >> 4, q = idx & 15;
    fx[k*20+q] = Bmat[(size_t)b*K*16 + idx];
  }
  for (int idx = tid; idx < 1536; idx += 256) wl[idx] = Wg[idx];
  if (tid < 96) bl[tid] = bg[tid];
  if (tid < 16) pwl[tid] = pw[tid];
  __syncthreads();

  int rows = M - m0; if (rows > 256) rows = 256;
  const int g = tid >> 2, sub = tid & 3;
  if (g < (rows >> 2)){
    const size_t lda = (amode == 0) ? 512 : 240;
    const float* arow = (amode == 0)
        ? Abase + (size_t)doc_ids[b] * 512 * 512
        : Abase + (size_t)b * 240 * 240;
    const float* r0 = arow + (size_t)(m0 + 4*g) * lda;
    float acc[4][16];
    #pragma unroll
    for (int r=0;r<4;r++)
      #pragma unroll
      for (int q=0;q<16;q++) acc[r][q] = 0.f;
    const int iters = K >> 4;
    for (int i = 0; i < iters; i++){
      const int kk = i*16 + sub*4;
      float4 a0 = *(const float4*)(r0 + kk);
      float4 a1 = *(const float4*)(r0 + lda + kk);
      float4 a2 = *(const float4*)(r0 + 2*lda + kk);
      float4 a3 = *(const float4*)(r0 + 3*lda + kk);
      float av[4][4] = {{a0.x,a0.y,a0.z,a0.w},{a1.x,a1.y,a1.z,a1.w},
                        {a2.x,a2.y,a2.z,a2.w},{a3.x,a3.y,a3.z,a3.w}};
      #pragma unroll
      for (int c = 0; c < 4; c++){
        const float* fr = &fx[(size_t)(kk + c)*20];
        float4 q0 = *(const float4*)(fr);
        float4 q1 = *(const float4*)(fr+4);
        float4 q2 = *(const float4*)(fr+8);
        float4 q3 = *(const float4*)(fr+12);
        float qv[16] = {q0.x,q0.y,q0.z,q0.w, q1.x,q1.y,q1.z,q1.w,
                        q2.x,q2.y,q2.z,q2.w, q3.x,q3.y,q3.z,q3.w};
        #pragma unroll
        for (int r = 0; r < 4; r++){
          const float aval = av[r][c];
          #pragma unroll
          for (int q = 0; q < 16; q++)
            acc[r][q] = fmaf(aval, qv[q], acc[r][q]);
        }
      }
    }
    #pragma unroll
    for (int r=0;r<4;r++)
      #pragma unroll
      for (int q=0;q<16;q++){
        float v = acc[r][q];
        v += __shfl_xor(v, 1);
        v += __shfl_xor(v, 2);
        acc[r][q] = v;
      }
    const int m = m0 + 4*g + sub;
    float a[16], x[16];
    #pragma unroll
    for (int q=0;q<16;q++)
      a[q] = (sub==0)?acc[0][q]:(sub==1)?acc[1][q]:(sub==2)?acc[2][q]:acc[3][q];
    {
      const float* xr = &fx[(size_t)m*20];
      float4 x0 = *(const float4*)(xr), x1 = *(const float4*)(xr+4);
      float4 x2v = *(const float4*)(xr+8), x3 = *(const float4*)(xr+12);
      x[0]=x0.x; x[1]=x0.y; x[2]=x0.z; x[3]=x0.w;
      x[4]=x1.x; x[5]=x1.y; x[6]=x1.z; x[7]=x1.w;
      x[8]=x2v.x; x[9]=x2v.y; x[10]=x2v.z; x[11]=x2v.w;
      x[12]=x3.x; x[13]=x3.y; x[14]=x3.z; x[15]=x3.w;
    }
    float z[16], rr[16];
    #pragma unroll
    for (int q=0;q<16;q++){
      const float s0 = bl[q] + bl[16+q]
                     + dot16(a, &wl[q*16]) + dot16(x, &wl[256 + q*16]);
      z[q] = sigf(s0);
      const float s1 = bl[32+q] + bl[48+q]
                     + dot16(a, &wl[512 + q*16]) + dot16(x, &wl[768 + q*16]);
      rr[q] = sigf(s1);
    }
    float rx[16];
    #pragma unroll
    for (int q=0;q<16;q++) rx[q] = rr[q]*x[q];
    float out[16]; float xp = 0.f;
    #pragma unroll
    for (int q=0;q<16;q++){
      const float s = bl[64+q] + bl[80+q]
                    + dot16(a, &wl[1024 + q*16]) + dot16(rx, &wl[1280 + q*16]);
      const float h = fmaxf(s, 0.f);
      const float o = h*z[q] + x[q]*(1.f - z[q]);
      out[q] = o;
      xp = fmaf(o, pwl[q], xp);
    }
    float* rp = &rep[((size_t)b*M + m)*16];
    *(float4*)(rp+0)  = make_float4(out[0],out[1],out[2],out[3]);
    *(float4*)(rp+4)  = make_float4(out[4],out[5],out[6],out[7]);
    *(float4*)(rp+8)  = make_float4(out[8],out[9],out[10],out[11]);
    *(float4*)(rp+12) = make_float4(out[12],out[13],out[14],out[15]);
    xproj[(size_t)b*M + m] = xp + pb[0];
  }
}

// ---------------- K3: adj@x2 -> scalar gate -> top-240 -> att_x1 ----------------
__global__ __launch_bounds__(256) void k_score1(
    const float* __restrict__ docs_adj, const int* __restrict__ doc_ids,
    const float* __restrict__ x2, const float* __restrict__ wsc,
    const float* __restrict__ bsc, const float* __restrict__ rep1,
    float* __restrict__ attx1, float* __restrict__ attx1T,
    int* __restrict__ idx1)
{
  alignas(16) __shared__ float xv[512];
  __shared__ float sval[512];
  __shared__ int sidx[512];
  const int tid = threadIdx.x, b = blockIdx.x;
  for (int i = tid; i < 512; i += 256) xv[i] = x2[(size_t)b*512 + i];
  __syncthreads();
  const float* abase = docs_adj + (size_t)doc_ids[b]*512*512;
  const int g = tid>>2, sub = tid&3;
  const float w0=wsc[0],w1=wsc[1],w2=wsc[2],w3=wsc[3],w4=wsc[4],w5=wsc[5];
  const float b0=bsc[0],b1=bsc[1],b2=bsc[2],b3=bsc[3],b4=bsc[4],b5=bsc[5];
  for (int p=0;p<8;p++){
    const int m = p*64 + g;
    const float* row = abase + (size_t)m*512;
    float s = 0.f;
    #pragma unroll 4
    for (int i=0;i<32;i++){
      const int kk = i*16 + sub*4;
      float4 a4 = *(const float4*)(row + kk);
      float4 xq = *(const float4*)(&xv[kk]);
      s = fmaf(a4.x,xq.x,s); s = fmaf(a4.y,xq.y,s);
      s = fmaf(a4.z,xq.z,s); s = fmaf(a4.w,xq.w,s);
    }
    s += __shfl_xor(s,1); s += __shfl_xor(s,2);
    if (sub == 0){
      const float x = xv[m];
      const float z = sigf(fmaf(s,w0,b0) + fmaf(x,w1,b1));
      const float r = sigf(fmaf(s,w2,b2) + fmaf(x,w3,b3));
      const float h = fmaxf(fmaf(s,w4,b4) + fmaf(r*x,w5,b5), 0.f);
      sval[m] = h*z + x*(1.f - z);
      sidx[m] = m;
    }
  }
  bitonic_desc<512>(sval, sidx);
  if (tid < K2_){
    const int rowi = sidx[tid];
    const float tv = tanhf(sval[tid]);
    const float* rr = &rep1[((size_t)b*512 + rowi)*16];
    float vs[16];
    #pragma unroll
    for (int q=0;q<16;q++) vs[q] = tv * rr[q];
    float* o = &attx1[((size_t)b*K2_ + tid)*16];
    #pragma unroll
    for (int q=0;q<16;q++) o[q] = vs[q];
    #pragma unroll
    for (int q=0;q<16;q++) attx1T[((size_t)b*16+q)*K2_ + tid] = vs[q];
    idx1[(size_t)b*K2_ + tid] = rowi;
  }
}

// ---------------- K4: adj_new = adj[idx][:,idx] ----------------
__global__ __launch_bounds__(256) void k_subadj(
    const float* __restrict__ docs_adj, const int* __restrict__ doc_ids,
    const int* __restrict__ idx1, float* __restrict__ adjnew)
{
  __shared__ int il[K2_];
  const int tid = threadIdx.x;
  const int b = blockIdx.x / 15, rb = blockIdx.x % 15;
  if (tid < K2_) il[tid] = idx1[(size_t)b*K2_ + tid];
  __syncthreads();
  const float* abase = docs_adj + (size_t)doc_ids[b]*512*512;
  const int r = rb*16 + (tid >> 4), jt = tid & 15;
  const float* row = abase + (size_t)il[r]*512;
  float* orow = adjnew + ((size_t)b*K2_ + r)*K2_;
  for (int p=0;p<15;p++){
    const int j = jt + p*16;
    orow[j] = row[il[j]];
  }
}

// ---------------- K6: adj_new@x4 -> scalar gate -> top-192 -> att_x2T ----------------
__global__ __launch_bounds__(256) void k_score2(
    const float* __restrict__ adjnew, const float* __restrict__ x4,
    const float* __restrict__ wsc, const float* __restrict__ bsc,
    const float* __restrict__ rep3, float* __restrict__ attx2T)
{
  alignas(16) __shared__ float xv[K2_];
  __shared__ float sval[256];
  __shared__ int sidx[256];
  const int tid = threadIdx.x, b = blockIdx.x;
  if (tid < K2_) xv[tid] = x4[(size_t)b*K2_ + tid];
  __syncthreads();
  const float* abase = adjnew + (size_t)b*K2_*K2_;
  const int g = tid>>2, sub = tid&3;
  const float w0=wsc[0],w1=wsc[1],w2=wsc[2],w3=wsc[3],w4=wsc[4],w5=wsc[5];
  const float b0=bsc[0],b1=bsc[1],b2=bsc[2],b3=bsc[3],b4=bsc[4],b5=bsc[5];
  for (int p=0;p<4;p++){
    const int m = p*64 + g;
    if (m < K2_){
      const float* row = abase + (size_t)m*K2_;
      float s = 0.f;
      #pragma unroll
      for (int i=0;i<15;i++){
        const int kk = i*16 + sub*4;
        float4 a4 = *(const float4*)(row + kk);
        float4 xq = *(const float4*)(&xv[kk]);
        s = fmaf(a4.x,xq.x,s); s = fmaf(a4.y,xq.y,s);
        s = fmaf(a4.z,xq.z,s); s = fmaf(a4.w,xq.w,s);
      }
      s += __shfl_xor(s,1); s += __shfl_xor(s,2);
      if (sub == 0){
        const float x = xv[m];
        const float z = sigf(fmaf(s,w0,b0) + fmaf(x,w1,b1));
        const float r = sigf(fmaf(s,w2,b2) + fmaf(x,w3,b3));
        const float h = fmaxf(fmaf(s,w4,b4) + fmaf(r*x,w5,b5), 0.f);
        sval[m] = h*z + x*(1.f - z);
        sidx[m] = m;
      }
    } else if (sub == 0){
      sval[m] = -3.402823466e38f; sidx[m] = 0x7fffffff;
    }
  }
  bitonic_desc<256>(sval, sidx);
  if (tid < K4_){
    const int rowi = sidx[tid];
    const float tv = tanhf(sval[tid]);
    const float* rr = &rep3[((size_t)b*K2_ + rowi)*16];
    #pragma unroll
    for (int q=0;q<16;q++) attx2T[((size_t)b*16+q)*K4_ + tid] = tv*rr[q];
  }
}

// ---------------- K7a: three sorted top-40s per (b,q) ----------------
__global__ __launch_bounds__(256) void k_topk40(
    const float* __restrict__ featqd, const float* __restrict__ attx1T,
    const float* __restrict__ attx2T, float* __restrict__ attcat)
{
  const int b = blockIdx.x / 12, part = blockIdx.x % 12;
  const int wave = threadIdx.x >> 6, lane = threadIdx.x & 63;
  const int task = part*4 + wave, arr = task >> 4, q = task & 15;
  const float* src; int n;
  if (arr == 0){ src = featqd + ((size_t)b*16 + q)*512; n = 512; }
  else if (arr == 1){ src = attx1T + ((size_t)b*16 + q)*K2_; n = K2_; }
  else { src = attx2T + ((size_t)b*16 + q)*K4_; n = K4_; }
  float v[8];
  #pragma unroll
  for (int i=0;i<8;i++){
    const int idx = lane + 64*i;
    v[i] = (idx < n) ? src[idx] : -3.402823466e38f;
  }
  float* outp = attcat + ((size_t)b*16 + q)*120 + arr*40;
  for (int it=0; it<40; it++){
    float lv = v[0]; int li = 0;
    #pragma unroll
    for (int i=1;i<8;i++) if (v[i] > lv){ lv = v[i]; li = i; }
    float bv = lv; int bc = li*64 + lane;
    #pragma unroll
    for (int off=1; off<64; off<<=1){
      const float ov = __shfl_xor(bv, off);
      const int oc = __shfl_xor(bc, off);
      if (ov > bv || (ov == bv && oc < bc)){ bv = ov; bc = oc; }
    }
    if (lane == (bc & 63)){
      const int slot = bc >> 6;
      #pragma unroll
      for (int i=0;i<8;i++) if (i == slot) v[i] = -3.402823466e38f;
    }
    if (lane == 0) outp[it] = bv;
  }
}

// ---------------- K7b: MLP + gated softmax + sum ----------------
__global__ __launch_bounds__(256) void k_mlp(
    const float* __restrict__ attcat,
    const float* __restrict__ l1w, const float* __restrict__ l1b,
    const float* __restrict__ l2w, const float* __restrict__ l2b,
    const float* __restrict__ l3w, const float* __restrict__ l3b,
    const float* __restrict__ idf, const float* __restrict__ gw,
    const float* __restrict__ gb, float* __restrict__ outp)
{
  alignas(16) __shared__ float w1l[64*124];
  alignas(16) __shared__ float w2l[32*68];
  alignas(16) __shared__ float attl[16*120];
  alignas(16) __shared__ float rel1[16*64];
  alignas(16) __shared__ float rel2[16*32];
  const int tid = threadIdx.x, b = blockIdx.x;
  for (int idx = tid; idx < 64*120; idx += 256){
    const int u = idx / 120, k = idx - u*120;
    w1l[u*124 + k] = l1w[idx];
  }
  for (int idx = tid; idx < 32*64; idx += 256){
    const int u = idx >> 6, k = idx & 63;
    w2l[u*68 + k] = l2w[idx];
  }
  for (int idx = tid; idx < 16*120; idx += 256)
    attl[idx] = attcat[(size_t)b*(16*120) + idx];
  __syncthreads();
  #pragma unroll
  for (int p=0;p<4;p++){
    const int idx = tid + p*256, q = idx >> 6, u = idx & 63;
    float acc = l1b[u];
    #pragma unroll
    for (int k4=0;k4<30;k4++){
      float4 av = *(const float4*)(&attl[q*120 + k4*4]);
      float4 wv = *(const float4*)(&w1l[u*124 + k4*4]);
      acc = fmaf(av.x,wv.x,acc); acc = fmaf(av.y,wv.y,acc);
      acc = fmaf(av.z,wv.z,acc); acc = fmaf(av.w,wv.w,acc);
    }
    rel1[q*64 + u] = fmaxf(acc, 0.f);
  }
  __syncthreads();
  #pragma unroll
  for (int p=0;p<2;p++){
    const int idx = tid + p*256, q = idx >> 5, u = idx & 31;
    float acc = l2b[u];
    #pragma unroll
    for (int k4=0;k4<16;k4++){
      float4 av = *(const float4*)(&rel1[q*64 + k4*4]);
      float4 wv = *(const float4*)(&w2l[u*68 + k4*4]);
      acc = fmaf(av.x,wv.x,acc); acc = fmaf(av.y,wv.y,acc);
      acc = fmaf(av.z,wv.z,acc); acc = fmaf(av.w,wv.w,acc);
    }
    rel2[q*32 + u] = fmaxf(acc, 0.f);
  }
  __syncthreads();
  if (tid < 16){
    float acc = l3b[0];
    #pragma unroll
    for (int k=0;k<32;k++) acc = fmaf(rel2[tid*32+k], l3w[k], acc);
    const float gv = fmaf(idf[(size_t)b*16 + tid], gw[0], gb[0]);
    float mx = gv;
    mx = fmaxf(mx, __shfl_xor(mx, 1));
    mx = fmaxf(mx, __shfl_xor(mx, 2));
    mx = fmaxf(mx, __shfl_xor(mx, 4));
    mx = fmaxf(mx, __shfl_xor(mx, 8));
    const float e = __expf(gv - mx);
    float se = e;
    se += __shfl_xor(se, 1); se += __shfl_xor(se, 2);
    se += __shfl_xor(se, 4); se += __shfl_xor(se, 8);
    float val = acc * (e / se);
    val += __shfl_xor(val, 1); val += __shfl_xor(val, 2);
    val += __shfl_xor(val, 4); val += __shfl_xor(val, 8);
    if (tid == 0) outp[b] = val;
  }
}

extern "C" void kernel_launch(void* const* d_in, const int* in_sizes, int n_in,
                              void* d_out, int out_size, void* d_ws, size_t ws_size,
                              hipStream_t stream)
{
  const float* emb  = (const float*)d_in[0];
  const int*   qtok = (const int*)d_in[1];
  const int*   dtok = (const int*)d_in[2];
  const int*   dids = (const int*)d_in[3];
  const float* dadj = (const float*)d_in[4];
  const float* idf  = (const float*)d_in[5];
  const float* Wg1  = (const float*)d_in[6];
  const float* bg1  = (const float*)d_in[7];
  const float* wg2  = (const float*)d_in[8];
  const float* bg2  = (const float*)d_in[9];
  const float* Wg3  = (const float*)d_in[10];
  const float* bg3  = (const float*)d_in[11];
  const float* wg4  = (const float*)d_in[12];
  const float* bg4  = (const float*)d_in[13];
  const float* p1w  = (const float*)d_in[14];
  const float* p1b  = (const float*)d_in[15];
  const float* p2w  = (const float*)d_in[16];
  const float* p2b  = (const float*)d_in[17];
  const float* l1w  = (const float*)d_in[18];
  const float* l1b  = (const float*)d_in[19];
  const float* l2w  = (const float*)d_in[20];
  const float* l2b  = (const float*)d_in[21];
  const float* l3w  = (const float*)d_in[22];
  const float* l3b  = (const float*)d_in[23];
  const float* gw   = (const float*)d_in[24];
  const float* gb   = (const float*)d_in[25];
  float* out = (float*)d_out;

  float* ws = (float*)d_ws;
  size_t off = 0;
  auto alloc = [&](size_t n)->float*{ float* p = ws + off; off += (n + 3) & ~(size_t)3; return p; };
  float* embinv = alloc(NW1);
  float* qen    = alloc((size_t)B_*QL_*ED_);
  float* featdq = alloc((size_t)B_*DL_*QL_);
  float* featqd = alloc((size_t)B_*DL_*QL_);
  float* rep1   = alloc((size_t)B_*DL_*QL_);
  float* x2     = alloc((size_t)B_*DL_);
  int*   idx1   = (int*)alloc((size_t)B_*K2_);
  float* attx1  = alloc((size_t)B_*K2_*QL_);
  float* attx1T = alloc((size_t)B_*K2_*QL_);
  float* adjnew = alloc((size_t)B_*K2_*K2_);
  float* rep3   = alloc((size_t)B_*K2_*QL_);
  float* x4     = alloc((size_t)B_*K2_);
  float* attx2T = alloc((size_t)B_*QL_*K4_);
  float* attcat = alloc((size_t)B_*QL_*120);

  k_qnorm<<<B_, 256, 0, stream>>>(emb, qtok, qen);
  k_enorm<<<(NW1+63)/64, 256, 0, stream>>>(emb, embinv);
  k_feat<<<B_*2, 256, 0, stream>>>(emb, embinv, dtok, qen, featdq, featqd);
  k_gemm_gate<<<B_*2, 256, (512*20+1536+96+16)*4, stream>>>(
      dadj, 0, dids, featdq, Wg1, bg1, p1w, p1b, rep1, x2, 512, 512, 2);
  k_score1<<<B_, 256, 0, stream>>>(dadj, dids, x2, wg2, bg2, rep1, attx1, attx1T, idx1);
  k_subadj<<<B_*15, 256, 0, stream>>>(dadj, dids, idx1, adjnew);
  k_gemm_gate<<<B_, 256, (240*20+1536+96+16)*4, stream>>>(
      adjnew, 1, dids, attx1, Wg3, bg3, p2w, p2b, rep3, x4, 240, 240, 1);
  k_score2<<<B_, 256, 0, stream>>>(adjnew, x4, wg4, bg4, rep3, attx2T);
  k_topk40<<<B_*12, 256, 0, stream>>>(featqd, attx1T, attx2T, attcat);
  k_mlp<<<B_, 256, 0, stream>>>(attcat, l1w, l1b, l2w, l2b, l3w, l3b, idf, gw, gb, out);
}